// Round 5
// baseline (366.502 us; speedup 1.0000x reference)
//
#include <hip/hip_runtime.h>
#include <hip/hip_bf16.h>

#define ALPHA 0.05f

constexpr int FULL = 4096;   // full in/out dim
constexpr int Mtot = 8192;   // B*S
constexpr int Kc   = 2048;   // active input channels
constexpr int Nc   = 2048;   // active output channels

typedef __hip_bfloat16 bf16_t;
using bf16x8 = __attribute__((ext_vector_type(8))) __bf16;
using f32x4  = __attribute__((ext_vector_type(4))) float;

__device__ __forceinline__ void gload_lds16(const bf16_t* g, bf16_t* l) {
  __builtin_amdgcn_global_load_lds(
      (const __attribute__((address_space(1))) void*)g,
      (__attribute__((address_space(3))) void*)l, 16, 0, 0);
}

// ---------- gather active cols of x -> bf16 A[Mtot][Kc], LDS-staged ----------
__global__ __launch_bounds__(256)
void k_convert_x(const float* __restrict__ x, const int* __restrict__ cols,
                 bf16_t* __restrict__ A) {
  __shared__ float xr[FULL];
  const int m = blockIdx.x, t = threadIdx.x;
  const float4* xg = reinterpret_cast<const float4*>(x + (size_t)m * FULL);
  float4* xl = reinterpret_cast<float4*>(xr);
#pragma unroll
  for (int i = 0; i < FULL / 1024; ++i) xl[t + i * 256] = xg[t + i * 256];
  __syncthreads();
  const int4 c0 = reinterpret_cast<const int4*>(cols)[t * 2];
  const int4 c1 = reinterpret_cast<const int4*>(cols)[t * 2 + 1];
  bf16_t tmp[8];
  tmp[0] = __float2bfloat16(xr[c0.x]);
  tmp[1] = __float2bfloat16(xr[c0.y]);
  tmp[2] = __float2bfloat16(xr[c0.z]);
  tmp[3] = __float2bfloat16(xr[c0.w]);
  tmp[4] = __float2bfloat16(xr[c1.x]);
  tmp[5] = __float2bfloat16(xr[c1.y]);
  tmp[6] = __float2bfloat16(xr[c1.z]);
  tmp[7] = __float2bfloat16(xr[c1.w]);
  reinterpret_cast<uint4*>(A + (size_t)m * Kc)[t] =
      *reinterpret_cast<const uint4*>(tmp);
}

// ---------- ALPHA*W -> bf16 Wb[Nc][Kc] ----------
__global__ void k_convert_w(const float* __restrict__ w, bf16_t* __restrict__ Wb) {
  int idx = blockIdx.x * blockDim.x + threadIdx.x;
  const float4* src = reinterpret_cast<const float4*>(w) + (size_t)idx * 2;
  float4 v0 = src[0], v1 = src[1];
  bf16_t tmp[8];
  tmp[0] = __float2bfloat16(v0.x * ALPHA);
  tmp[1] = __float2bfloat16(v0.y * ALPHA);
  tmp[2] = __float2bfloat16(v0.z * ALPHA);
  tmp[3] = __float2bfloat16(v0.w * ALPHA);
  tmp[4] = __float2bfloat16(v1.x * ALPHA);
  tmp[5] = __float2bfloat16(v1.y * ALPHA);
  tmp[6] = __float2bfloat16(v1.z * ALPHA);
  tmp[7] = __float2bfloat16(v1.w * ALPHA);
  *reinterpret_cast<uint4*>(&Wb[(size_t)idx * 8]) =
      *reinterpret_cast<const uint4*>(tmp);
}

// ---------- bias fill (fallback path only) ----------
__global__ void k_bias_fill(const float* __restrict__ bias, float* __restrict__ out) {
  int idx = blockIdx.x * blockDim.x + threadIdx.x;
  const float4 v = reinterpret_cast<const float4*>(bias)[idx & (FULL / 4 - 1)];
  reinterpret_cast<float4*>(out)[idx] = v;
}

// =================== 3-buffer counted-vmcnt MFMA GEMM ===================
// BM=256 x BN=128 x BK=64, 512 thr (8 waves 2Mx4N), LDS 3x48KiB.
// T2: LDS swizzle byte^=((row&7)<<4) via pre-swizzled global src (rule 21).
// T4: counted vmcnt(6) at tile boundaries (tile t+2 stays in flight).
// T5: setprio around MFMA cluster.
constexpr int BM2 = 256, BN2 = 128, BK2 = 64;
constexpr int NT2 = Kc / BK2;        // 32 K-tiles
constexpr int G_M2 = Mtot / BM2;     // 32
constexpr int G_N2 = Nc / BN2;       // 16
constexpr int NWG2 = G_M2 * G_N2;    // 512

__global__ __launch_bounds__(512, 1)
void k_gemm8(const bf16_t* __restrict__ A, const bf16_t* __restrict__ Wb,
             float* __restrict__ yc) {
  __shared__ __align__(16) bf16_t As[3][BM2 * BK2];  // 3 x 32 KiB
  __shared__ __align__(16) bf16_t Bs[3][BN2 * BK2];  // 3 x 16 KiB

  // XCD supertile swizzle (bijective: 8 xcd x 4 bm x 16 bn)
  const int bid = blockIdx.x;
  const int xcd = bid & 7, lid = bid >> 3;   // lid in [0,64)
  const int st = lid >> 4, wi = lid & 15;
  const int gm0 = (xcd * 4 + (wi >> 2)) * BM2;
  const int gn0 = (st * 4 + (wi & 3)) * BN2;

  const int t = threadIdx.x;
  const int w = t >> 6, l = t & 63;          // wave id / lane
  const int wr = w >> 2, wc = w & 3;         // wave 2Mx4N
  const int lr = l & 15, lq = l >> 4;
  // staging source pre-swizzle: lane l covers row (w*8 + l>>3) of each 64-row
  // slab; fetches global col-block ((l&7)^(l>>3)) so that the LINEAR LDS write
  // (base + lane*16B) realizes LDS[r][p*8] = global[r][(p^(r&7))*8].
  const int swz = ((l & 7) ^ (l >> 3)) * 8;  // bf16 elements

  const bf16_t* aSrc = A  + (size_t)(gm0 + w * 8 + (l >> 3)) * Kc + swz;
  const bf16_t* bSrc = Wb + (size_t)(gn0 + w * 8 + (l >> 3)) * Kc + swz;

#define STAGE8(bi, k0)                                                        \
  do {                                                                        \
    _Pragma("unroll") for (int j = 0; j < 4; ++j)                             \
        gload_lds16(aSrc + (size_t)j * 64 * Kc + (k0),                        \
                    &As[bi][(j * 64 + w * 8) * 64]);                          \
    _Pragma("unroll") for (int j = 0; j < 2; ++j)                             \
        gload_lds16(bSrc + (size_t)j * 64 * Kc + (k0),                        \
                    &Bs[bi][(j * 64 + w * 8) * 64]);                          \
  } while (0)

  f32x4 acc[8][2] = {};

  STAGE8(0, 0);
  STAGE8(1, 64);
  asm volatile("s_waitcnt vmcnt(6)" ::: "memory");  // tile0 landed
  __builtin_amdgcn_s_barrier();
  __builtin_amdgcn_sched_barrier(0);

  for (int tt = 0; tt < NT2; ++tt) {
    const int cur = tt % 3;
    if (tt + 2 < NT2) {
      const int nb = (tt + 2) % 3;
      STAGE8(nb, (tt + 2) * BK2);
    }
    const bf16_t* Ab = As[cur];
    const bf16_t* Bb = Bs[cur];
#pragma unroll
    for (int kk = 0; kk < 2; ++kk) {
      // swizzled k-offset: (kk*32 + lq*8) ^ ((l&7)*8), row&7 == l&7 for all frags
      const int ko = (kk * 32 + lq * 8) ^ ((l & 7) << 3);
      bf16x8 af[8], bf[2];
#pragma unroll
      for (int mi = 0; mi < 8; ++mi)
        af[mi] = *reinterpret_cast<const bf16x8*>(
            &Ab[(wr * 128 + mi * 16 + lr) * BK2 + ko]);
#pragma unroll
      for (int ni = 0; ni < 2; ++ni)
        bf[ni] = *reinterpret_cast<const bf16x8*>(
            &Bb[(wc * 32 + ni * 16 + lr) * BK2 + ko]);
      asm volatile("s_waitcnt lgkmcnt(0)" ::: "memory");
      __builtin_amdgcn_sched_barrier(0);  // rule 18: keep MFMA below the wait
      __builtin_amdgcn_s_setprio(1);
#pragma unroll
      for (int mi = 0; mi < 8; ++mi)
#pragma unroll
        for (int ni = 0; ni < 2; ++ni)
          acc[mi][ni] = __builtin_amdgcn_mfma_f32_16x16x32_bf16(
              af[mi], bf[ni], acc[mi][ni], 0, 0, 0);
      __builtin_amdgcn_s_setprio(0);
      __builtin_amdgcn_sched_barrier(0);
    }
    // tile boundary: ensure tile tt+1 landed. Counted: tile tt+2's 6 loads
    // stay in flight (FIFO drain => oldest 6 = tile tt+1 complete).
    if (tt + 2 < NT2)
      asm volatile("s_waitcnt vmcnt(6)" ::: "memory");
    else
      asm volatile("s_waitcnt vmcnt(0)" ::: "memory");
    __builtin_amdgcn_s_barrier();
    __builtin_amdgcn_sched_barrier(0);
  }
#undef STAGE8

  // epilogue: C/D layout col = lane&15, row = lq*4 + j  [m89/m91-verified]
  const int mbase = gm0 + wr * 128 + lq * 4;
  const int nbase = gn0 + wc * 32 + lr;
#pragma unroll
  for (int ni = 0; ni < 2; ++ni) {
    int n = nbase + ni * 16;
#pragma unroll
    for (int mi = 0; mi < 8; ++mi)
#pragma unroll
      for (int j = 0; j < 4; ++j)
        yc[(size_t)(mbase + mi * 16 + j) * Nc + n] = acc[mi][ni][j];
  }
}

// ---------- legacy m97-style GEMM (small-ws fallback, scattered epilogue) ----
constexpr int BM = 128, BN = 128, BK = 64;
constexpr int GRID_N = Nc / BN;
constexpr int NWG = GRID_N * (Mtot / BM);

__global__ __launch_bounds__(256)
void k_gemm_fb(const bf16_t* __restrict__ A, const bf16_t* __restrict__ Wb,
               const float* __restrict__ bias, const int* __restrict__ rows,
               float* __restrict__ out) {
  __shared__ __align__(16) bf16_t As[BM * BK];
  __shared__ __align__(16) bf16_t Bs[BN * BK];
  const int bid = blockIdx.x;
  const int wgid = (bid & 7) * (NWG / 8) + (bid >> 3);
  const int bm0 = (wgid / GRID_N) * BM, bn0 = (wgid % GRID_N) * BN;
  const int t = threadIdx.x;
  const int w = t >> 6, l = t & 63;
  const int wm = (w >> 1) * 64, wn = (w & 1) * 64;
  const bf16_t* srcA[4];
  const bf16_t* srcB[4];
#pragma unroll
  for (int i = 0; i < 4; ++i) {
    int elem = i * 2048 + t * 8;
    int row = elem >> 6, col = elem & 63;
    srcA[i] = A + (size_t)(bm0 + row) * Kc + col;
    srcB[i] = Wb + (size_t)(bn0 + row) * Kc + col;
  }
  f32x4 acc[4][4] = {};
  for (int k0 = 0; k0 < Kc; k0 += BK) {
#pragma unroll
    for (int i = 0; i < 4; ++i) {
      gload_lds16(srcA[i] + k0, As + i * 2048 + w * 512);
      gload_lds16(srcB[i] + k0, Bs + i * 2048 + w * 512);
    }
    __syncthreads();
    const int r = l & 15;
#pragma unroll
    for (int kk = 0; kk < 2; ++kk) {
      const int ko = kk * 32 + (l >> 4) * 8;
      bf16x8 af[4], bf[4];
#pragma unroll
      for (int mi = 0; mi < 4; ++mi)
        af[mi] = *reinterpret_cast<const bf16x8*>(&As[(wm + mi * 16 + r) * BK + ko]);
#pragma unroll
      for (int ni = 0; ni < 4; ++ni)
        bf[ni] = *reinterpret_cast<const bf16x8*>(&Bs[(wn + ni * 16 + r) * BK + ko]);
#pragma unroll
      for (int mi = 0; mi < 4; ++mi)
#pragma unroll
        for (int ni = 0; ni < 4; ++ni)
          acc[mi][ni] = __builtin_amdgcn_mfma_f32_16x16x32_bf16(
              af[mi], bf[ni], acc[mi][ni], 0, 0, 0);
    }
    __syncthreads();
  }
  const int lr = (l >> 4) * 4, lc = l & 15;
#pragma unroll
  for (int ni = 0; ni < 4; ++ni) {
    int nc = bn0 + wn + ni * 16 + lc;
    int oc = rows[nc];
    float bv = bias[oc];
#pragma unroll
    for (int mi = 0; mi < 4; ++mi)
#pragma unroll
      for (int j = 0; j < 4; ++j)
        out[(size_t)(bm0 + wm + mi * 16 + lr + j) * FULL + oc] =
            acc[mi][ni][j] + bv;
  }
}

// ---------- fused zero-scatter + bias ----------
__global__ __launch_bounds__(256)
void k_output(const float* __restrict__ yc, const float* __restrict__ bias,
              const int* __restrict__ rows, float* __restrict__ out) {
  __shared__ float row[FULL];
  const int m = blockIdx.x, t = threadIdx.x;
  const float4 z4 = {0.f, 0.f, 0.f, 0.f};
  float4* rl = reinterpret_cast<float4*>(row);
#pragma unroll
  for (int i = 0; i < FULL / 1024; ++i) rl[t + i * 256] = z4;
  __syncthreads();
  const float4* ycr = reinterpret_cast<const float4*>(yc + (size_t)m * Nc);
#pragma unroll
  for (int i = 0; i < Nc / 1024; ++i) {
    int idx = t + i * 256;
    float4 v = ycr[idx];
    int4 rr = reinterpret_cast<const int4*>(rows)[idx];
    row[rr.x] = v.x;
    row[rr.y] = v.y;
    row[rr.z] = v.z;
    row[rr.w] = v.w;
  }
  __syncthreads();
  float4* orow = reinterpret_cast<float4*>(out + (size_t)m * FULL);
  const float4* b4 = reinterpret_cast<const float4*>(bias);
#pragma unroll
  for (int i = 0; i < FULL / 1024; ++i) {
    int idx = t + i * 256;
    float4 r = rl[idx];
    float4 b = b4[idx];
    r.x += b.x; r.y += b.y; r.z += b.z; r.w += b.w;
    orow[idx] = r;
  }
}

// ---------- naive fallback ----------
__global__ void k_gemm_naive(const float* __restrict__ x, const float* __restrict__ wgt,
                             const float* __restrict__ bias, const int* __restrict__ rows,
                             const int* __restrict__ cols, float* __restrict__ out) {
  int idx = blockIdx.x * blockDim.x + threadIdx.x;
  int m = idx / Nc, n = idx - (idx / Nc) * Nc;
  const float* xr = x + (size_t)m * FULL;
  const float* wr = wgt + (size_t)n * Kc;
  float s = 0.f;
  for (int k = 0; k < Kc; ++k) s += xr[cols[k]] * wr[k];
  int oc = rows[n];
  out[(size_t)m * FULL + oc] = s * ALPHA + bias[oc];
}

extern "C" void kernel_launch(void* const* d_in, const int* in_sizes, int n_in,
                              void* d_out, int out_size, void* d_ws, size_t ws_size,
                              hipStream_t stream) {
  const float* x    = (const float*)d_in[0];
  const float* wgt  = (const float*)d_in[1];
  const float* bias = (const float*)d_in[2];
  const int*   rows = (const int*)d_in[3];
  const int*   cols = (const int*)d_in[4];
  float* out = (float*)d_out;

  const size_t needA = (size_t)Mtot * Kc * sizeof(bf16_t);  // 32 MiB
  const size_t needW = (size_t)Nc * Kc * sizeof(bf16_t);    //  8 MiB
  const size_t needY = (size_t)Mtot * Nc * sizeof(float);   // 64 MiB

  if (ws_size >= needA + needW + needY) {
    bf16_t* Abf = (bf16_t*)d_ws;
    bf16_t* Wbf = (bf16_t*)((char*)d_ws + needA);
    float*  yc  = (float*)((char*)d_ws + needA + needW);
    k_convert_x<<<Mtot, 256, 0, stream>>>(x, cols, Abf);
    k_convert_w<<<(Nc * (Kc / 8)) / 256, 256, 0, stream>>>(wgt, Wbf);
    k_gemm8<<<NWG2, 512, 0, stream>>>(Abf, Wbf, yc);
    k_output<<<Mtot, 256, 0, stream>>>(yc, bias, rows, out);
  } else if (ws_size >= needA + needW) {
    bf16_t* Abf = (bf16_t*)d_ws;
    bf16_t* Wbf = (bf16_t*)((char*)d_ws + needA);
    k_convert_x<<<Mtot, 256, 0, stream>>>(x, cols, Abf);
    k_convert_w<<<(Nc * (Kc / 8)) / 256, 256, 0, stream>>>(wgt, Wbf);
    k_bias_fill<<<(Mtot * (FULL / 4)) / 256, 256, 0, stream>>>(bias, out);
    k_gemm_fb<<<NWG, 256, 0, stream>>>(Abf, Wbf, bias, rows, out);
  } else {
    k_bias_fill<<<(Mtot * (FULL / 4)) / 256, 256, 0, stream>>>(bias, out);
    k_gemm_naive<<<(Mtot * Nc) / 256, 256, 0, stream>>>(x, wgt, bias, rows, cols, out);
  }
}

// Round 6
// 343.894 us; speedup vs baseline: 1.0657x; 1.0657x over previous
//
#include <hip/hip_runtime.h>
#include <hip/hip_bf16.h>

#define ALPHA 0.05f

constexpr int FULL = 4096;   // full in/out dim
constexpr int Mtot = 8192;   // B*S
constexpr int Kc   = 2048;   // active input channels
constexpr int Nc   = 2048;   // active output channels

typedef __hip_bfloat16 bf16_t;
using bf16x8 = __attribute__((ext_vector_type(8))) __bf16;
using f32x4  = __attribute__((ext_vector_type(4))) float;

__device__ __forceinline__ void gload_lds16(const bf16_t* g, bf16_t* l) {
  __builtin_amdgcn_global_load_lds(
      (const __attribute__((address_space(1))) void*)g,
      (__attribute__((address_space(3))) void*)l, 16, 0, 0);
}

// ---------- gather active cols of x -> bf16 A[Mtot][Kc] ----------
// 4 rows/block, double-buffered LDS row staging, cols regs amortized.
__global__ __launch_bounds__(256)
void k_convert_x(const float* __restrict__ x, const int* __restrict__ cols,
                 bf16_t* __restrict__ A) {
  __shared__ float xr[2][FULL];
  const int t = threadIdx.x;
  const int m0 = blockIdx.x * 4;
  const int4 c0 = reinterpret_cast<const int4*>(cols)[t * 2];
  const int4 c1 = reinterpret_cast<const int4*>(cols)[t * 2 + 1];
  {
    const float4* xg = reinterpret_cast<const float4*>(x + (size_t)m0 * FULL);
    float4* xl = reinterpret_cast<float4*>(xr[0]);
#pragma unroll
    for (int i = 0; i < 4; ++i) xl[t + i * 256] = xg[t + i * 256];
  }
  __syncthreads();
#pragma unroll
  for (int r = 0; r < 4; ++r) {
    float4 g0, g1, g2, g3;
    if (r < 3) {  // prefetch next row into regs (latency hides under gather)
      const float4* xn =
          reinterpret_cast<const float4*>(x + (size_t)(m0 + r + 1) * FULL);
      g0 = xn[t]; g1 = xn[t + 256]; g2 = xn[t + 512]; g3 = xn[t + 768];
    }
    const float* cur = xr[r & 1];
    bf16_t tmp[8];
    tmp[0] = __float2bfloat16(cur[c0.x]);
    tmp[1] = __float2bfloat16(cur[c0.y]);
    tmp[2] = __float2bfloat16(cur[c0.z]);
    tmp[3] = __float2bfloat16(cur[c0.w]);
    tmp[4] = __float2bfloat16(cur[c1.x]);
    tmp[5] = __float2bfloat16(cur[c1.y]);
    tmp[6] = __float2bfloat16(cur[c1.z]);
    tmp[7] = __float2bfloat16(cur[c1.w]);
    reinterpret_cast<uint4*>(A + (size_t)(m0 + r) * Kc)[t] =
        *reinterpret_cast<const uint4*>(tmp);
    if (r < 3) {
      __syncthreads();  // all gathers of row r done before overwriting other buf
      float4* xw = reinterpret_cast<float4*>(xr[(r + 1) & 1]);
      xw[t] = g0; xw[t + 256] = g1; xw[t + 512] = g2; xw[t + 768] = g3;
      __syncthreads();
    }
  }
}

// ---------- ALPHA*W -> bf16 Wb[Nc][Kc] ----------
__global__ void k_convert_w(const float* __restrict__ w, bf16_t* __restrict__ Wb) {
  int idx = blockIdx.x * blockDim.x + threadIdx.x;
  const float4* src = reinterpret_cast<const float4*>(w) + (size_t)idx * 2;
  float4 v0 = src[0], v1 = src[1];
  bf16_t tmp[8];
  tmp[0] = __float2bfloat16(v0.x * ALPHA);
  tmp[1] = __float2bfloat16(v0.y * ALPHA);
  tmp[2] = __float2bfloat16(v0.z * ALPHA);
  tmp[3] = __float2bfloat16(v0.w * ALPHA);
  tmp[4] = __float2bfloat16(v1.x * ALPHA);
  tmp[5] = __float2bfloat16(v1.y * ALPHA);
  tmp[6] = __float2bfloat16(v1.z * ALPHA);
  tmp[7] = __float2bfloat16(v1.w * ALPHA);
  *reinterpret_cast<uint4*>(&Wb[(size_t)idx * 8]) =
      *reinterpret_cast<const uint4*>(tmp);
}

// ---------- bias fill (fallback path only) ----------
__global__ void k_bias_fill(const float* __restrict__ bias, float* __restrict__ out) {
  int idx = blockIdx.x * blockDim.x + threadIdx.x;
  const float4 v = reinterpret_cast<const float4*>(bias)[idx & (FULL / 4 - 1)];
  reinterpret_cast<float4*>(out)[idx] = v;
}

// =================== 8-phase 256x256 MFMA GEMM (T2+T3+T4+T5) ===================
// 8 waves 2Mx4N, per-wave 128x64 out, BK=64, 2-K-tile dbuf LDS (128 KiB).
// Per K-tile 4 quadrant-phases w/ register fragment reuse: reads {12,4,8,0}.
// Half-tile stage points chosen region-safe: B-halves dead after ph1 (staged
// ph2), A-halves dead after ph2 (staged ph3), next-tile B1 at ph0 (other buf).
// Counted vmcnt(6) at K-tile boundary only (3 half-tiles in flight).
constexpr int BM3 = 256, BN3 = 256, BK3 = 64;
constexpr int NT3 = Kc / BK3;            // 32
constexpr int NWG3 = (Mtot / BM3) * (Nc / BN3);  // 32*8 = 256 = 1 wg/CU

__global__ __launch_bounds__(512, 1)
void k_gemm8(const bf16_t* __restrict__ A, const bf16_t* __restrict__ Wb,
             float* __restrict__ yc) {
  __shared__ __align__(16) bf16_t As3[2][BM3 * BK3];  // 2 x 32 KiB
  __shared__ __align__(16) bf16_t Bs3[2][BN3 * BK3];  // 2 x 32 KiB

  // XCD supertile swizzle: xcd owns 4 M-tiles x 8 N-tiles
  const int bid = blockIdx.x;
  const int xcd = bid & 7, lid = bid >> 3;       // lid in [0,32)
  const int gm0 = (xcd * 4 + (lid >> 3)) * BM3;
  const int gn0 = (lid & 7) * BN3;

  const int t = threadIdx.x;
  const int w = t >> 6, l = t & 63;
  const int w8 = w * 8;
  const int wr = w >> 2, wc = w & 3;             // wave 2Mx4N
  const int lr = l & 15, lq = l >> 4;
  const int xorv = (l & 7) << 3;                 // read-side swizzle (elems)
  const int swz = ((l & 7) ^ (l >> 3)) * 8;      // pre-swizzled source col

  const bf16_t* aB = A  + (size_t)(gm0 + w8 + (l >> 3)) * Kc + swz;
  const bf16_t* bB = Wb + (size_t)(gn0 + w8 + (l >> 3)) * Kc + swz;

#define STG_A(bi, half, kt)                                                     \
  do {                                                                          \
    gload_lds16(aB + (size_t)((half) * 128) * Kc + (kt) * 64,                   \
                &As3[bi][(((half) * 128) + w8) * 64]);                          \
    gload_lds16(aB + (size_t)((half) * 128 + 64) * Kc + (kt) * 64,              \
                &As3[bi][(((half) * 128 + 64) + w8) * 64]);                     \
  } while (0)
#define STG_B(bi, half, kt)                                                     \
  do {                                                                          \
    gload_lds16(bB + (size_t)((half) * 128) * Kc + (kt) * 64,                   \
                &Bs3[bi][(((half) * 128) + w8) * 64]);                          \
    gload_lds16(bB + (size_t)((half) * 128 + 64) * Kc + (kt) * 64,              \
                &Bs3[bi][(((half) * 128 + 64) + w8) * 64]);                     \
  } while (0)

  f32x4 acc[8][4] = {};
  bf16x8 afl[4][2], afh[4][2], bfl[2][2], bfh[2][2];

  // prologue: tile0 full + tile1 {B0, A0, A1}; B1(t1) comes at ph0 of tile 0
  STG_A(0, 0, 0); STG_A(0, 1, 0); STG_B(0, 0, 0); STG_B(0, 1, 0);
  STG_B(1, 0, 1); STG_A(1, 0, 1); STG_A(1, 1, 1);
  asm volatile("s_waitcnt vmcnt(6)" ::: "memory");  // tile0 landed
  __builtin_amdgcn_s_barrier();
  __builtin_amdgcn_sched_barrier(0);

  for (int tt = 0; tt < NT3; ++tt) {
    const int cur = tt & 1, nxt = cur ^ 1;
    const bf16_t* Ap = As3[cur];
    const bf16_t* Bp = Bs3[cur];

    // ---- phase 0: read afl(8)+bfl(4); stage B1(t+1) -> other buf ----
#pragma unroll
    for (int mi = 0; mi < 4; ++mi)
#pragma unroll
      for (int kk = 0; kk < 2; ++kk)
        afl[mi][kk] = *reinterpret_cast<const bf16x8*>(
            &Ap[(wr * 128 + mi * 16 + lr) * 64 + ((kk * 32 + lq * 8) ^ xorv)]);
#pragma unroll
    for (int ni = 0; ni < 2; ++ni)
#pragma unroll
      for (int kk = 0; kk < 2; ++kk)
        bfl[ni][kk] = *reinterpret_cast<const bf16x8*>(
            &Bp[(wc * 64 + ni * 16 + lr) * 64 + ((kk * 32 + lq * 8) ^ xorv)]);
    if (tt + 1 < NT3) STG_B(nxt, 1, tt + 1);
    asm volatile("s_waitcnt lgkmcnt(8)" ::: "memory");
    __builtin_amdgcn_s_barrier();
    asm volatile("s_waitcnt lgkmcnt(0)" ::: "memory");
    __builtin_amdgcn_sched_barrier(0);
    __builtin_amdgcn_s_setprio(1);
#pragma unroll
    for (int mi = 0; mi < 4; ++mi)
#pragma unroll
      for (int ni = 0; ni < 2; ++ni)
#pragma unroll
        for (int kk = 0; kk < 2; ++kk)
          acc[mi][ni] = __builtin_amdgcn_mfma_f32_16x16x32_bf16(
              afl[mi][kk], bfl[ni][kk], acc[mi][ni], 0, 0, 0);
    __builtin_amdgcn_s_setprio(0);
    __builtin_amdgcn_s_barrier();

    // ---- phase 1: read bfh(4); reuse afl ----
#pragma unroll
    for (int ni = 0; ni < 2; ++ni)
#pragma unroll
      for (int kk = 0; kk < 2; ++kk)
        bfh[ni][kk] = *reinterpret_cast<const bf16x8*>(
            &Bp[(wc * 64 + (ni + 2) * 16 + lr) * 64 +
                ((kk * 32 + lq * 8) ^ xorv)]);
    __builtin_amdgcn_s_barrier();
    asm volatile("s_waitcnt lgkmcnt(0)" ::: "memory");
    __builtin_amdgcn_sched_barrier(0);
    __builtin_amdgcn_s_setprio(1);
#pragma unroll
    for (int mi = 0; mi < 4; ++mi)
#pragma unroll
      for (int ni = 0; ni < 2; ++ni)
#pragma unroll
        for (int kk = 0; kk < 2; ++kk)
          acc[mi][ni + 2] = __builtin_amdgcn_mfma_f32_16x16x32_bf16(
              afl[mi][kk], bfh[ni][kk], acc[mi][ni + 2], 0, 0, 0);
    __builtin_amdgcn_s_setprio(0);
    __builtin_amdgcn_s_barrier();

    // ---- phase 2: read afh(8); reuse bfh; stage B0(t+2) (B dead after ph1) --
#pragma unroll
    for (int mi = 0; mi < 4; ++mi)
#pragma unroll
      for (int kk = 0; kk < 2; ++kk)
        afh[mi][kk] = *reinterpret_cast<const bf16x8*>(
            &Ap[(wr * 128 + (mi + 4) * 16 + lr) * 64 +
                ((kk * 32 + lq * 8) ^ xorv)]);
    if (tt + 2 < NT3) STG_B(cur, 0, tt + 2);
    __builtin_amdgcn_s_barrier();
    asm volatile("s_waitcnt lgkmcnt(0)" ::: "memory");
    __builtin_amdgcn_sched_barrier(0);
    __builtin_amdgcn_s_setprio(1);
#pragma unroll
    for (int mi = 0; mi < 4; ++mi)
#pragma unroll
      for (int ni = 0; ni < 2; ++ni)
#pragma unroll
        for (int kk = 0; kk < 2; ++kk)
          acc[mi + 4][ni + 2] = __builtin_amdgcn_mfma_f32_16x16x32_bf16(
              afh[mi][kk], bfh[ni][kk], acc[mi + 4][ni + 2], 0, 0, 0);
    __builtin_amdgcn_s_setprio(0);
    __builtin_amdgcn_s_barrier();

    // ---- phase 3: no reads; reuse afh+bfl; stage A0,A1(t+2) (A dead) ----
    if (tt + 2 < NT3) { STG_A(cur, 0, tt + 2); STG_A(cur, 1, tt + 2); }
    __builtin_amdgcn_s_barrier();
    __builtin_amdgcn_s_setprio(1);
#pragma unroll
    for (int mi = 0; mi < 4; ++mi)
#pragma unroll
      for (int ni = 0; ni < 2; ++ni)
#pragma unroll
        for (int kk = 0; kk < 2; ++kk)
          acc[mi + 4][ni] = __builtin_amdgcn_mfma_f32_16x16x32_bf16(
              afh[mi][kk], bfl[ni][kk], acc[mi + 4][ni], 0, 0, 0);
    __builtin_amdgcn_s_setprio(0);
    // K-tile boundary: tile t+1 complete; keep 3 half-tiles (6 loads) in flight
    if (tt + 2 < NT3)
      asm volatile("s_waitcnt vmcnt(6)" ::: "memory");
    else if (tt + 1 < NT3)
      asm volatile("s_waitcnt vmcnt(0)" ::: "memory");
    __builtin_amdgcn_s_barrier();
    __builtin_amdgcn_sched_barrier(0);
  }
#undef STG_A
#undef STG_B

  // epilogue: C/D layout col = lane&15, row = lq*4 + j  [m89/m91-verified]
  const int mbase = gm0 + wr * 128 + lq * 4;
  const int nbase = gn0 + wc * 64 + lr;
#pragma unroll
  for (int ni = 0; ni < 4; ++ni) {
    int n = nbase + ni * 16;
#pragma unroll
    for (int mi = 0; mi < 8; ++mi)
#pragma unroll
      for (int j = 0; j < 4; ++j)
        yc[(size_t)(mbase + mi * 16 + j) * Nc + n] = acc[mi][ni][j];
  }
}

// ---------- fused zero-scatter + bias: 4 rows/block, dbuf pipeline ----------
__global__ __launch_bounds__(256)
void k_output(const float* __restrict__ yc, const float* __restrict__ bias,
              const int* __restrict__ rows, float* __restrict__ out) {
  __shared__ float rbuf[2][FULL];  // 32 KiB
  const int t = threadIdx.x;
  const int m0 = blockIdx.x * 4;
  const int4 ra = reinterpret_cast<const int4*>(rows)[t];
  const int4 rb = reinterpret_cast<const int4*>(rows)[t + 256];
  float4 bv0 = reinterpret_cast<const float4*>(bias)[t];
  float4 bv1 = reinterpret_cast<const float4*>(bias)[t + 256];
  float4 bv2 = reinterpret_cast<const float4*>(bias)[t + 512];
  float4 bv3 = reinterpret_cast<const float4*>(bias)[t + 768];

  // prologue: zero buf0, scatter row0
  {
    const float4 z4 = {0.f, 0.f, 0.f, 0.f};
    float4* rl = reinterpret_cast<float4*>(rbuf[0]);
#pragma unroll
    for (int i = 0; i < 4; ++i) rl[t + i * 256] = z4;
    __syncthreads();
    const float4* ycr = reinterpret_cast<const float4*>(yc + (size_t)m0 * Nc);
    float4 ya = ycr[t], yb = ycr[t + 256];
    rbuf[0][ra.x] = ya.x; rbuf[0][ra.y] = ya.y;
    rbuf[0][ra.z] = ya.z; rbuf[0][ra.w] = ya.w;
    rbuf[0][rb.x] = yb.x; rbuf[0][rb.y] = yb.y;
    rbuf[0][rb.z] = yb.z; rbuf[0][rb.w] = yb.w;
    __syncthreads();
  }
#pragma unroll
  for (int r = 0; r < 4; ++r) {
    const int cur = r & 1, nx = cur ^ 1;
    float4 ya, yb;
    if (r < 3) {  // prefetch next yc row + zero next buf
      const float4* ycn =
          reinterpret_cast<const float4*>(yc + (size_t)(m0 + r + 1) * Nc);
      ya = ycn[t]; yb = ycn[t + 256];
      const float4 z4 = {0.f, 0.f, 0.f, 0.f};
      float4* rl = reinterpret_cast<float4*>(rbuf[nx]);
#pragma unroll
      for (int i = 0; i < 4; ++i) rl[t + i * 256] = z4;
    }
    __syncthreads();  // zero(nx) done; scatter(r) [prev iter] already done
    // write out row r = rbuf[cur] + bias (coalesced)
    float4* orow = reinterpret_cast<float4*>(out + (size_t)(m0 + r) * FULL);
    const float4* rl = reinterpret_cast<const float4*>(rbuf[cur]);
    float4 v0 = rl[t], v1 = rl[t + 256], v2 = rl[t + 512], v3 = rl[t + 768];
    v0.x += bv0.x; v0.y += bv0.y; v0.z += bv0.z; v0.w += bv0.w;
    v1.x += bv1.x; v1.y += bv1.y; v1.z += bv1.z; v1.w += bv1.w;
    v2.x += bv2.x; v2.y += bv2.y; v2.z += bv2.z; v2.w += bv2.w;
    v3.x += bv3.x; v3.y += bv3.y; v3.z += bv3.z; v3.w += bv3.w;
    orow[t] = v0; orow[t + 256] = v1; orow[t + 512] = v2; orow[t + 768] = v3;
    if (r < 3) {  // scatter next row into zeroed buf
      float* rn = rbuf[nx];
      rn[ra.x] = ya.x; rn[ra.y] = ya.y; rn[ra.z] = ya.z; rn[ra.w] = ya.w;
      rn[rb.x] = yb.x; rn[rb.y] = yb.y; rn[rb.z] = yb.z; rn[rb.w] = yb.w;
      __syncthreads();
    }
  }
}

// ---------- legacy m97-style GEMM (small-ws fallback, scattered epilogue) ----
constexpr int BM = 128, BN = 128, BK = 64;
constexpr int GRID_N = Nc / BN;
constexpr int NWG = GRID_N * (Mtot / BM);

__global__ __launch_bounds__(256)
void k_gemm_fb(const bf16_t* __restrict__ A, const bf16_t* __restrict__ Wb,
               const float* __restrict__ bias, const int* __restrict__ rows,
               float* __restrict__ out) {
  __shared__ __align__(16) bf16_t As[BM * BK];
  __shared__ __align__(16) bf16_t Bs[BN * BK];
  const int bid = blockIdx.x;
  const int wgid = (bid & 7) * (NWG / 8) + (bid >> 3);
  const int bm0 = (wgid / GRID_N) * BM, bn0 = (wgid % GRID_N) * BN;
  const int t = threadIdx.x;
  const int w = t >> 6, l = t & 63;
  const int wm = (w >> 1) * 64, wn = (w & 1) * 64;
  const bf16_t* srcA[4];
  const bf16_t* srcB[4];
#pragma unroll
  for (int i = 0; i < 4; ++i) {
    int elem = i * 2048 + t * 8;
    int row = elem >> 6, col = elem & 63;
    srcA[i] = A + (size_t)(bm0 + row) * Kc + col;
    srcB[i] = Wb + (size_t)(bn0 + row) * Kc + col;
  }
  f32x4 acc[4][4] = {};
  for (int k0 = 0; k0 < Kc; k0 += BK) {
#pragma unroll
    for (int i = 0; i < 4; ++i) {
      gload_lds16(srcA[i] + k0, As + i * 2048 + w * 512);
      gload_lds16(srcB[i] + k0, Bs + i * 2048 + w * 512);
    }
    __syncthreads();
    const int r = l & 15;
#pragma unroll
    for (int kk = 0; kk < 2; ++kk) {
      const int ko = kk * 32 + (l >> 4) * 8;
      bf16x8 af[4], bf[4];
#pragma unroll
      for (int mi = 0; mi < 4; ++mi)
        af[mi] = *reinterpret_cast<const bf16x8*>(&As[(wm + mi * 16 + r) * BK + ko]);
#pragma unroll
      for (int ni = 0; ni < 4; ++ni)
        bf[ni] = *reinterpret_cast<const bf16x8*>(&Bs[(wn + ni * 16 + r) * BK + ko]);
#pragma unroll
      for (int mi = 0; mi < 4; ++mi)
#pragma unroll
        for (int ni = 0; ni < 4; ++ni)
          acc[mi][ni] = __builtin_amdgcn_mfma_f32_16x16x32_bf16(
              af[mi], bf[ni], acc[mi][ni], 0, 0, 0);
    }
    __syncthreads();
  }
  const int lr = (l >> 4) * 4, lc = l & 15;
#pragma unroll
  for (int ni = 0; ni < 4; ++ni) {
    int nc = bn0 + wn + ni * 16 + lc;
    int oc = rows[nc];
    float bv = bias[oc];
#pragma unroll
    for (int mi = 0; mi < 4; ++mi)
#pragma unroll
      for (int j = 0; j < 4; ++j)
        out[(size_t)(bm0 + wm + mi * 16 + lr + j) * FULL + oc] =
            acc[mi][ni][j] + bv;
  }
}

// ---------- naive fallback ----------
__global__ void k_gemm_naive(const float* __restrict__ x, const float* __restrict__ wgt,
                             const float* __restrict__ bias, const int* __restrict__ rows,
                             const int* __restrict__ cols, float* __restrict__ out) {
  int idx = blockIdx.x * blockDim.x + threadIdx.x;
  int m = idx / Nc, n = idx - (idx / Nc) * Nc;
  const float* xr = x + (size_t)m * FULL;
  const float* wr = wgt + (size_t)n * Kc;
  float s = 0.f;
  for (int k = 0; k < Kc; ++k) s += xr[cols[k]] * wr[k];
  int oc = rows[n];
  out[(size_t)m * FULL + oc] = s * ALPHA + bias[oc];
}

extern "C" void kernel_launch(void* const* d_in, const int* in_sizes, int n_in,
                              void* d_out, int out_size, void* d_ws, size_t ws_size,
                              hipStream_t stream) {
  const float* x    = (const float*)d_in[0];
  const float* wgt  = (const float*)d_in[1];
  const float* bias = (const float*)d_in[2];
  const int*   rows = (const int*)d_in[3];
  const int*   cols = (const int*)d_in[4];
  float* out = (float*)d_out;

  const size_t needA = (size_t)Mtot * Kc * sizeof(bf16_t);  // 32 MiB
  const size_t needW = (size_t)Nc * Kc * sizeof(bf16_t);    //  8 MiB
  const size_t needY = (size_t)Mtot * Nc * sizeof(float);   // 64 MiB

  if (ws_size >= needA + needW + needY) {
    bf16_t* Abf = (bf16_t*)d_ws;
    bf16_t* Wbf = (bf16_t*)((char*)d_ws + needA);
    float*  yc  = (float*)((char*)d_ws + needA + needW);
    k_convert_x<<<Mtot / 4, 256, 0, stream>>>(x, cols, Abf);
    k_convert_w<<<(Nc * (Kc / 8)) / 256, 256, 0, stream>>>(wgt, Wbf);
    k_gemm8<<<NWG3, 512, 0, stream>>>(Abf, Wbf, yc);
    k_output<<<Mtot / 4, 256, 0, stream>>>(yc, bias, rows, out);
  } else if (ws_size >= needA + needW) {
    bf16_t* Abf = (bf16_t*)d_ws;
    bf16_t* Wbf = (bf16_t*)((char*)d_ws + needA);
    k_convert_x<<<Mtot / 4, 256, 0, stream>>>(x, cols, Abf);
    k_convert_w<<<(Nc * (Kc / 8)) / 256, 256, 0, stream>>>(wgt, Wbf);
    k_bias_fill<<<(Mtot * (FULL / 4)) / 256, 256, 0, stream>>>(bias, out);
    k_gemm_fb<<<NWG, 256, 0, stream>>>(Abf, Wbf, bias, rows, out);
  } else {
    k_bias_fill<<<(Mtot * (FULL / 4)) / 256, 256, 0, stream>>>(bias, out);
    k_gemm_naive<<<(Mtot * Nc) / 256, 256, 0, stream>>>(x, wgt, bias, rows, cols, out);
  }
}